// Round 5
// baseline (152.505 us; speedup 1.0000x reference)
//
#include <hip/hip_runtime.h>
#include <math.h>

#define WIN 11
#define IMG_H 384
#define IMG_W 512
#define OUT_H (IMG_H - WIN + 1)   // 374
#define OUT_W (IMG_W - WIN + 1)   // 502
#define RPW 2                     // output rows per wave
#define WAVES_PER_BLOCK 4
#define ROWS_PER_BLOCK (RPW * WAVES_PER_BLOCK)        // 8
#define BANDS_PER_IMG ((OUT_H + ROWS_PER_BLOCK - 1) / ROWS_PER_BLOCK)  // 47
#define NIMG 48
#define NBLOCKS (BANDS_PER_IMG * NIMG)                // 2256
#define BLOCKS_PER_XCD (NBLOCKS / 8)                  // 282
#define NBUCKETS 256

struct GaussW { float g[WIN]; };

__device__ __forceinline__ void horiz11(const float (&acc)[8], float (&out)[8],
                                        int lane, const GaussW& gw)
{
    float v[18];
    #pragma unroll
    for (int j = 0; j < 8; ++j) v[j] = acc[j];
    #pragma unroll
    for (int j = 0; j < 8; ++j) v[8 + j] = __shfl(acc[j], lane + 1, 64);
    v[16] = __shfl(acc[0], lane + 2, 64);
    v[17] = __shfl(acc[1], lane + 2, 64);
    #pragma unroll
    for (int j = 0; j < 8; ++j) {
        float o = 0.f;
        #pragma unroll
        for (int k = 0; k < WIN; ++k) o = fmaf(gw.g[k], v[j + k], o);
        out[j] = o;
    }
}

__device__ __forceinline__ float row_ssim(float (&acc)[5][8], int lane, int c0,
                                          const GaussW& gw)
{
    float h[5][8];
    #pragma unroll
    for (int ch = 0; ch < 5; ++ch) horiz11(acc[ch], h[ch], lane, gw);
    const float C1 = 1e-4f, C2 = 9e-4f;
    float s = 0.f;
    #pragma unroll
    for (int j = 0; j < 8; ++j) {
        float mu1 = h[0][j], mu2 = h[1][j];
        float mu1s = mu1 * mu1, mu2s = mu2 * mu2, m12 = mu1 * mu2;
        float s1  = h[2][j] - mu1s;
        float s2  = h[3][j] - mu2s;
        float s12 = h[4][j] - m12;
        float num = fmaf(2.f, m12, C1) * fmaf(2.f, s12, C2);
        float den = (mu1s + mu2s + C1) * (s1 + s2 + C2);
        float ssim = num * __builtin_amdgcn_rcpf(den);
        s += (c0 + j < OUT_W) ? ssim : 0.f;
    }
    return s;
}

__global__ __launch_bounds__(64 * WAVES_PER_BLOCK) void ssim_fused_kernel(
    const float* __restrict__ X, const float* __restrict__ Y,
    double* __restrict__ accum, GaussW gw)
{
    const int wave = threadIdx.x >> 6;
    const int lane = threadIdx.x & 63;

    // XCD-aware swizzle: dispatch is round-robin id%8 across XCDs; give each
    // XCD a CONTIGUOUS run of (img, band) work so the 10-row halo overlap
    // between adjacent bands hits that XCD's private 4 MB L2.
    const int id   = blockIdx.x;
    const int wid  = (id & 7) * BLOCKS_PER_XCD + (id >> 3);
    const int img  = wid / BANDS_PER_IMG;
    const int band = wid % BANDS_PER_IMG;
    const int r0   = band * ROWS_PER_BLOCK + wave * RPW;  // first output row

    const int c0 = lane << 3;   // this lane's 8 columns
    const float* __restrict__ Xb = X + ((size_t)img * IMG_H) * IMG_W + c0;
    const float* __restrict__ Yb = Y + ((size_t)img * IMG_H) * IMG_W + c0;

    // ---- vertical 11-tap, 2 output rows per wave, streaming 12 input rows ----
    float a[RPW][5][8];
    #pragma unroll
    for (int r = 0; r < RPW; ++r)
        #pragma unroll
        for (int ch = 0; ch < 5; ++ch)
            #pragma unroll
            for (int j = 0; j < 8; ++j) a[r][ch][j] = 0.f;

    #pragma unroll
    for (int k = 0; k < RPW + WIN - 1; ++k) {   // 12 input rows
        int gr = r0 + k; gr = gr < IMG_H - 1 ? gr : IMG_H - 1;
        const float* rx = Xb + (size_t)gr * IMG_W;
        const float* ry = Yb + (size_t)gr * IMG_W;
        float4 xa = *(const float4*)(rx);
        float4 xb = *(const float4*)(rx + 4);
        float4 ya = *(const float4*)(ry);
        float4 yb = *(const float4*)(ry + 4);
        float xs[8] = {xa.x, xa.y, xa.z, xa.w, xb.x, xb.y, xb.z, xb.w};
        float ys[8] = {ya.x, ya.y, ya.z, ya.w, yb.x, yb.y, yb.z, yb.w};
        #pragma unroll
        for (int r = 0; r < RPW; ++r) {
            if (k - r >= 0 && k - r < WIN) {     // compile-time after unroll
                const float g = gw.g[k - r];
                #pragma unroll
                for (int j = 0; j < 8; ++j) {
                    float x = xs[j], y = ys[j];
                    a[r][0][j] = fmaf(g, x, a[r][0][j]);
                    a[r][1][j] = fmaf(g, y, a[r][1][j]);
                    float t = g * x;
                    a[r][2][j] = fmaf(t, x, a[r][2][j]);
                    a[r][4][j] = fmaf(t, y, a[r][4][j]);
                    float u = g * y;
                    a[r][3][j] = fmaf(u, y, a[r][3][j]);
                }
            }
        }
    }

    // ---- horizontal + epilogue per row (wave-uniform row mask) ----
    float sum = 0.f;
    #pragma unroll
    for (int r = 0; r < RPW; ++r)
        if (r0 + r < OUT_H)
            sum += row_ssim(a[r], lane, c0, gw);

    // ---- wave reduction -> one f64 atomic per wave, bucketed ----
    #pragma unroll
    for (int off = 32; off; off >>= 1)
        sum += __shfl_down(sum, off, 64);
    if (lane == 0) {
        int gwid = id * WAVES_PER_BLOCK + wave;
        atomicAdd(&accum[gwid & (NBUCKETS - 1)], (double)sum);
    }
}

__global__ void ssim_finalize_kernel(const double* __restrict__ accum,
                                     float* __restrict__ out, double inv_count)
{
    const int lane = threadIdx.x;
    double s = 0.0;
    for (int i = lane; i < NBUCKETS; i += 64) s += accum[i];
    #pragma unroll
    for (int off = 32; off; off >>= 1)
        s += __shfl_down(s, off, 64);
    if (lane == 0) out[0] = (float)(1.0 - s * inv_count);
}

extern "C" void kernel_launch(void* const* d_in, const int* in_sizes, int n_in,
                              void* d_out, int out_size, void* d_ws, size_t ws_size,
                              hipStream_t stream) {
    const float* X = (const float*)d_in[0];
    const float* Y = (const float*)d_in[1];
    float* out = (float*)d_out;
    double* accum = (double*)d_ws;

    GaussW gw;
    {
        double g[WIN], ssum = 0.0;
        for (int i = 0; i < WIN; ++i) {
            double d = (double)i - WIN / 2;
            g[i] = exp(-(d * d) / (2.0 * 1.5 * 1.5));
            ssum += g[i];
        }
        for (int i = 0; i < WIN; ++i) gw.g[i] = (float)(g[i] / ssum);
    }

    // d_ws is re-poisoned 0xAA before every call — zero the buckets.
    hipMemsetAsync(accum, 0, NBUCKETS * sizeof(double), stream);

    ssim_fused_kernel<<<NBLOCKS, 64 * WAVES_PER_BLOCK, 0, stream>>>(X, Y, accum, gw);

    const double inv_count = 1.0 / ((double)(NIMG) * OUT_H * OUT_W);
    ssim_finalize_kernel<<<1, 64, 0, stream>>>(accum, out, inv_count);
}

// Round 6
// 133.036 us; speedup vs baseline: 1.1463x; 1.1463x over previous
//
#include <hip/hip_runtime.h>
#include <math.h>

#define WIN 11
#define IMG_H 384
#define IMG_W 512
#define OUT_H (IMG_H - WIN + 1)   // 374
#define OUT_W (IMG_W - WIN + 1)   // 502
#define RPW 2                     // output rows per wave
#define NPAIRS (OUT_H / RPW)      // 187 (exact: 374 = 2*187)
#define NIMG 48
#define NBLOCKS (NPAIRS * NIMG)   // 8976 one-wave blocks
#define BLOCKS_PER_XCD (NBLOCKS / 8)  // 1122
#define NBUCKETS 256

struct GaussW { float g[WIN]; };

__device__ __forceinline__ void horiz11(const float (&acc)[8], float (&out)[8],
                                        int lane, const GaussW& gw)
{
    float v[18];
    #pragma unroll
    for (int j = 0; j < 8; ++j) v[j] = acc[j];
    #pragma unroll
    for (int j = 0; j < 8; ++j) v[8 + j] = __shfl(acc[j], lane + 1, 64);
    v[16] = __shfl(acc[0], lane + 2, 64);
    v[17] = __shfl(acc[1], lane + 2, 64);
    #pragma unroll
    for (int j = 0; j < 8; ++j) {
        float o = 0.f;
        #pragma unroll
        for (int k = 0; k < WIN; ++k) o = fmaf(gw.g[k], v[j + k], o);
        out[j] = o;
    }
}

__device__ __forceinline__ float row_ssim(float (&acc)[5][8], int lane, int c0,
                                          const GaussW& gw)
{
    float h[5][8];
    #pragma unroll
    for (int ch = 0; ch < 5; ++ch) horiz11(acc[ch], h[ch], lane, gw);
    const float C1 = 1e-4f, C2 = 9e-4f;
    float s = 0.f;
    #pragma unroll
    for (int j = 0; j < 8; ++j) {
        float mu1 = h[0][j], mu2 = h[1][j];
        float mu1s = mu1 * mu1, mu2s = mu2 * mu2, m12 = mu1 * mu2;
        float s1  = h[2][j] - mu1s;
        float s2  = h[3][j] - mu2s;
        float s12 = h[4][j] - m12;
        float num = fmaf(2.f, m12, C1) * fmaf(2.f, s12, C2);
        float den = (mu1s + mu2s + C1) * (s1 + s2 + C2);
        float ssim = num * __builtin_amdgcn_rcpf(den);
        s += (c0 + j < OUT_W) ? ssim : 0.f;
    }
    return s;
}

// 64-thread (1-wave) blocks; min 4 waves/EU pins VGPR <= 128 (the m69
// occupancy cliff: 129+ VGPR steps the allocator to 2 waves/SIMD).
__global__ __launch_bounds__(64, 4) void ssim_fused_kernel(
    const float* __restrict__ X, const float* __restrict__ Y,
    double* __restrict__ accum, GaussW gw)
{
    const int lane = threadIdx.x & 63;

    // XCD-aware swizzle: dispatch is round-robin id%8 across XCDs; give each
    // XCD a CONTIGUOUS run of (img, row-pair) work so the 10-row halo overlap
    // between adjacent row-pairs hits that XCD's private 4 MB L2.
    const int id   = blockIdx.x;
    const int wid  = (id & 7) * BLOCKS_PER_XCD + (id >> 3);
    const int img  = wid / NPAIRS;
    const int pair = wid % NPAIRS;
    const int r0   = pair * RPW;          // first output row (no clamp needed:
                                          // max r0+11 = 383 = IMG_H-1)
    const int c0 = lane << 3;             // this lane's 8 columns
    const float* __restrict__ Xb = X + ((size_t)img * IMG_H + r0) * IMG_W + c0;
    const float* __restrict__ Yb = Y + ((size_t)img * IMG_H + r0) * IMG_W + c0;

    // ---- vertical 11-tap, 2 output rows, streaming 12 input rows ----
    float a[RPW][5][8];
    #pragma unroll
    for (int r = 0; r < RPW; ++r)
        #pragma unroll
        for (int ch = 0; ch < 5; ++ch)
            #pragma unroll
            for (int j = 0; j < 8; ++j) a[r][ch][j] = 0.f;

    #pragma unroll
    for (int k = 0; k < RPW + WIN - 1; ++k) {   // 12 input rows
        const float* rx = Xb + (size_t)k * IMG_W;
        const float* ry = Yb + (size_t)k * IMG_W;
        float4 xa = *(const float4*)(rx);
        float4 xb = *(const float4*)(rx + 4);
        float4 ya = *(const float4*)(ry);
        float4 yb = *(const float4*)(ry + 4);
        float xs[8] = {xa.x, xa.y, xa.z, xa.w, xb.x, xb.y, xb.z, xb.w};
        float ys[8] = {ya.x, ya.y, ya.z, ya.w, yb.x, yb.y, yb.z, yb.w};
        #pragma unroll
        for (int r = 0; r < RPW; ++r) {
            if (k - r >= 0 && k - r < WIN) {     // compile-time after unroll
                const float g = gw.g[k - r];
                #pragma unroll
                for (int j = 0; j < 8; ++j) {
                    float x = xs[j], y = ys[j];
                    a[r][0][j] = fmaf(g, x, a[r][0][j]);
                    a[r][1][j] = fmaf(g, y, a[r][1][j]);
                    float t = g * x;
                    a[r][2][j] = fmaf(t, x, a[r][2][j]);
                    a[r][4][j] = fmaf(t, y, a[r][4][j]);
                    float u = g * y;
                    a[r][3][j] = fmaf(u, y, a[r][3][j]);
                }
            }
        }
    }

    // ---- horizontal + epilogue (both rows always in-range: 374 = 2*187) ----
    float sum = row_ssim(a[0], lane, c0, gw) + row_ssim(a[1], lane, c0, gw);

    // ---- wave reduction -> one f64 atomic per wave, bucketed ----
    #pragma unroll
    for (int off = 32; off; off >>= 1)
        sum += __shfl_down(sum, off, 64);
    if (lane == 0)
        atomicAdd(&accum[id & (NBUCKETS - 1)], (double)sum);
}

__global__ void ssim_finalize_kernel(const double* __restrict__ accum,
                                     float* __restrict__ out, double inv_count)
{
    const int lane = threadIdx.x;
    double s = 0.0;
    for (int i = lane; i < NBUCKETS; i += 64) s += accum[i];
    #pragma unroll
    for (int off = 32; off; off >>= 1)
        s += __shfl_down(s, off, 64);
    if (lane == 0) out[0] = (float)(1.0 - s * inv_count);
}

extern "C" void kernel_launch(void* const* d_in, const int* in_sizes, int n_in,
                              void* d_out, int out_size, void* d_ws, size_t ws_size,
                              hipStream_t stream) {
    const float* X = (const float*)d_in[0];
    const float* Y = (const float*)d_in[1];
    float* out = (float*)d_out;
    double* accum = (double*)d_ws;

    GaussW gw;
    {
        double g[WIN], ssum = 0.0;
        for (int i = 0; i < WIN; ++i) {
            double d = (double)i - WIN / 2;
            g[i] = exp(-(d * d) / (2.0 * 1.5 * 1.5));
            ssum += g[i];
        }
        for (int i = 0; i < WIN; ++i) gw.g[i] = (float)(g[i] / ssum);
    }

    // d_ws is re-poisoned 0xAA before every call — zero the buckets.
    hipMemsetAsync(accum, 0, NBUCKETS * sizeof(double), stream);

    ssim_fused_kernel<<<NBLOCKS, 64, 0, stream>>>(X, Y, accum, gw);

    const double inv_count = 1.0 / ((double)(NIMG) * OUT_H * OUT_W);
    ssim_finalize_kernel<<<1, 64, 0, stream>>>(accum, out, inv_count);
}